// Round 1
// baseline (585.101 us; speedup 1.0000x reference)
//
#include <hip/hip_runtime.h>
#include <hip/hip_bf16.h>

#define N_NODES 100000
#define N_EDGES 600000
#define N_LABELS 200000
#define DIM 128
#define NPAD 100032          // 1563 * 64  (GEMM row-tile padding)
#define NPARTS 391           // ceil(N_NODES/256)

using short8 = __attribute__((ext_vector_type(8))) short;
using f32x4  = __attribute__((ext_vector_type(4))) float;

// ---------------- conversion kernels ----------------

__global__ void convert_emb_k(const float* __restrict__ emb, __hip_bfloat16* __restrict__ out) {
    long i = (long)blockIdx.x * blockDim.x + threadIdx.x;   // covers NPAD*DIM exactly
    float v = (i < (long)N_NODES * DIM) ? emb[i] : 0.f;
    out[i] = __float2bfloat16(v);
}

// Build B^T (256 x 128): cols 0..127 = Wl, 128..255 = Wr, row-major in K
__global__ void convert_w_k(const float* __restrict__ Wl, const float* __restrict__ Wr,
                            __hip_bfloat16* __restrict__ BT) {
    int i = blockIdx.x * blockDim.x + threadIdx.x;          // 256*128 threads
    int n = i >> 7;
    int k = i & 127;
    float v = (n < 128) ? Wl[k * 128 + n] : Wr[k * 128 + (n - 128)];
    BT[n * 128 + k] = __float2bfloat16(v);
}

// ---------------- CSR build ----------------

__global__ void count_k(const int* __restrict__ ei, int* __restrict__ cnt) {
    int e = blockIdx.x * blockDim.x + threadIdx.x;
    if (e < N_EDGES) atomicAdd(&cnt[ei[N_EDGES + e]], 1);
}

__global__ void scan1_k(const int* __restrict__ cnt, int* __restrict__ rowptr,
                        int* __restrict__ partials) {
    __shared__ int s[256];
    int t = threadIdx.x;
    int i = blockIdx.x * 256 + t;
    int v = (i < N_NODES) ? cnt[i] : 0;
    s[t] = v;
    __syncthreads();
    for (int off = 1; off < 256; off <<= 1) {
        int x = s[t];
        int y = (t >= off) ? s[t - off] : 0;
        __syncthreads();
        s[t] = x + y;
        __syncthreads();
    }
    if (i < N_NODES) rowptr[i] = s[t] - v;      // block-local exclusive
    if (t == 255) partials[blockIdx.x] = s[255];
}

__global__ void scan2_k(const int* __restrict__ partials, int* __restrict__ pscan,
                        int* __restrict__ rowptr) {
    __shared__ int s[512];
    int t = threadIdx.x;
    int v = (t < NPARTS) ? partials[t] : 0;
    s[t] = v;
    __syncthreads();
    for (int off = 1; off < 512; off <<= 1) {
        int x = s[t];
        int y = (t >= off) ? s[t - off] : 0;
        __syncthreads();
        s[t] = x + y;
        __syncthreads();
    }
    if (t < NPARTS) pscan[t] = s[t] - v;        // exclusive across blocks
    if (t == 511) rowptr[N_NODES] = s[511];     // total = N_EDGES
}

__global__ void scan3_k(int* __restrict__ rowptr, const int* __restrict__ pscan,
                        int* __restrict__ widx) {
    int i = blockIdx.x * 256 + threadIdx.x;
    if (i < N_NODES) {
        int v = rowptr[i] + pscan[i >> 8];
        rowptr[i] = v;
        widx[i] = v;
    }
}

__global__ void fill_k(const int* __restrict__ ei, int* __restrict__ widx,
                       int* __restrict__ adj) {
    int e = blockIdx.x * blockDim.x + threadIdx.x;
    if (e < N_EDGES) {
        int d = ei[N_EDGES + e];
        int pos = atomicAdd(&widx[d], 1);
        adj[pos] = ei[e];
    }
}

// ---------------- GEMM: C[NPAD x 256] = A[NPAD x 128] @ [Wl | Wr]  (bf16, MFMA) ----------------

__global__ __launch_bounds__(256) void gemm_k(const __hip_bfloat16* __restrict__ A,
                                              const __hip_bfloat16* __restrict__ BT,
                                              __hip_bfloat16* __restrict__ C) {
    int lane = threadIdx.x & 63;
    int wave = threadIdx.x >> 6;
    int quad = lane >> 4;
    int l16  = lane & 15;
    long rowbase = (long)blockIdx.x * 64 + wave * 16;

    f32x4 acc[16];
#pragma unroll
    for (int t = 0; t < 16; ++t)
#pragma unroll
        for (int r = 0; r < 4; ++r) acc[t][r] = 0.f;

    const short* Ax = (const short*)A;
    const short* Bx = (const short*)BT;

#pragma unroll
    for (int kk = 0; kk < 4; ++kk) {
        // A-frag: A[rowbase + l16][kk*32 + quad*8 + j], j=0..7 (16B contiguous)
        short8 a = *(const short8*)(Ax + (rowbase + l16) * DIM + kk * 32 + quad * 8);
#pragma unroll
        for (int t = 0; t < 16; ++t) {
            // B-frag: BT[t*16 + l16][kk*32 + quad*8 + j] == B[k][n]
            short8 b = *(const short8*)(Bx + (t * 16 + l16) * DIM + kk * 32 + quad * 8);
            acc[t] = __builtin_amdgcn_mfma_f32_16x16x32_bf16(a, b, acc[t], 0, 0, 0);
        }
    }

    // C/D layout: row = quad*4 + r, col = l16
#pragma unroll
    for (int t = 0; t < 16; ++t)
#pragma unroll
        for (int r = 0; r < 4; ++r) {
            long row = rowbase + quad * 4 + r;
            C[row * 256 + t * 16 + l16] = __float2bfloat16(acc[t][r]);
        }
}

// ---------------- layer-1 aggregation: x1 = relu(mean(Hl[nbrs]) + Hr + b1), bf16 out ----------------

__global__ void agg1_k(const __hip_bfloat16* __restrict__ H, const int* __restrict__ rowptr,
                       const int* __restrict__ adj, const float* __restrict__ b1,
                       __hip_bfloat16* __restrict__ x1) {
    int node = blockIdx.x * 2 + (threadIdx.x >> 7);
    int f = threadIdx.x & 127;
    if (node >= N_NODES) {                        // zero the GEMM pad rows
        if (node < NPAD) x1[(long)node * DIM + f] = __float2bfloat16(0.f);
        return;
    }
    int beg = rowptr[node], end = rowptr[node + 1];
    float sum = 0.f;
    for (int e = beg; e < end; ++e) {
        int s = adj[e];
        sum += __bfloat162float(H[(long)s * 256 + f]);
    }
    int deg = end - beg;
    float inv = deg > 0 ? 1.f / (float)deg : 0.f;
    float v = sum * inv + __bfloat162float(H[(long)node * 256 + 128 + f]) + b1[f];
    x1[(long)node * DIM + f] = __float2bfloat16(fmaxf(v, 0.f));
}

// ---------------- layer-2 aggregation fused with link predictor projections ----------------

__global__ void agg2_k(const __hip_bfloat16* __restrict__ H, const int* __restrict__ rowptr,
                       const int* __restrict__ adj, const float* __restrict__ b2,
                       const float* __restrict__ Wlin, float* __restrict__ p,
                       float* __restrict__ q) {
    __shared__ float sp[2][128];
    __shared__ float sq[2][128];
    int half = threadIdx.x >> 7;
    int node = blockIdx.x * 2 + half;             // grid = N_NODES/2 exactly (N even)
    int f = threadIdx.x & 127;
    int beg = rowptr[node], end = rowptr[node + 1];
    float sum = 0.f;
    for (int e = beg; e < end; ++e)
        sum += __bfloat162float(H[(long)adj[e] * 256 + f]);
    int deg = end - beg;
    float inv = deg > 0 ? 1.f / (float)deg : 0.f;
    float v = sum * inv + __bfloat162float(H[(long)node * 256 + 128 + f]) + b2[f];
    sp[half][f] = v * Wlin[f];
    sq[half][f] = v * Wlin[128 + f];
    __syncthreads();
    for (int s2 = 64; s2 > 0; s2 >>= 1) {
        if (f < s2) {
            sp[half][f] += sp[half][f + s2];
            sq[half][f] += sq[half][f + s2];
        }
        __syncthreads();
    }
    if (f == 0) { p[node] = sp[half][0]; q[node] = sq[half][0]; }
}

__global__ void out_k(const int* __restrict__ eli, const float* __restrict__ p,
                      const float* __restrict__ q, const float* __restrict__ blin,
                      float* __restrict__ out) {
    int i = blockIdx.x * blockDim.x + threadIdx.x;
    if (i < N_LABELS) out[i] = p[eli[i]] + q[eli[N_LABELS + i]] + blin[0];
}

// ---------------- launch ----------------

extern "C" void kernel_launch(void* const* d_in, const int* in_sizes, int n_in,
                              void* d_out, int out_size, void* d_ws, size_t ws_size,
                              hipStream_t stream) {
    const int*   edge_index = (const int*)d_in[0];
    const int*   eli        = (const int*)d_in[1];
    const float* emb        = (const float*)d_in[2];
    const float* W1l        = (const float*)d_in[3];
    const float* b1         = (const float*)d_in[4];
    const float* W1r        = (const float*)d_in[5];
    const float* W2l        = (const float*)d_in[6];
    const float* b2         = (const float*)d_in[7];
    const float* W2r        = (const float*)d_in[8];
    const float* Wlin       = (const float*)d_in[9];
    const float* blin       = (const float*)d_in[10];
    float* out = (float*)d_out;

    char* ws = (char*)d_ws;
    size_t off = 0;
    auto alloc = [&](size_t bytes) -> void* {
        off = (off + 255) & ~(size_t)255;
        void* ptr = ws + off;
        off += bytes;
        return ptr;
    };

    __hip_bfloat16* emb_bf = (__hip_bfloat16*)alloc((size_t)NPAD * DIM * 2);
    __hip_bfloat16* H      = (__hip_bfloat16*)alloc((size_t)NPAD * 256 * 2);  // reused for both layers
    __hip_bfloat16* x1     = (__hip_bfloat16*)alloc((size_t)NPAD * DIM * 2);
    __hip_bfloat16* BT1    = (__hip_bfloat16*)alloc(256 * 128 * 2);
    __hip_bfloat16* BT2    = (__hip_bfloat16*)alloc(256 * 128 * 2);
    int* cnt      = (int*)alloc((size_t)N_NODES * 4);
    int* rowptr   = (int*)alloc((size_t)(N_NODES + 1) * 4);
    int* widx     = (int*)alloc((size_t)N_NODES * 4);
    int* adj      = (int*)alloc((size_t)N_EDGES * 4);
    int* partials = (int*)alloc(NPARTS * 4);
    int* pscan    = (int*)alloc(NPARTS * 4);
    float* p      = (float*)alloc((size_t)N_NODES * 4);
    float* q      = (float*)alloc((size_t)N_NODES * 4);

    hipMemsetAsync(cnt, 0, (size_t)N_NODES * 4, stream);

    // conversions
    convert_emb_k<<<(NPAD * DIM) / 256, 256, 0, stream>>>(emb, emb_bf);
    convert_w_k<<<128, 256, 0, stream>>>(W1l, W1r, BT1);
    convert_w_k<<<128, 256, 0, stream>>>(W2l, W2r, BT2);

    // CSR build
    count_k<<<(N_EDGES + 255) / 256, 256, 0, stream>>>(edge_index, cnt);
    scan1_k<<<NPARTS, 256, 0, stream>>>(cnt, rowptr, partials);
    scan2_k<<<1, 512, 0, stream>>>(partials, pscan, rowptr);
    scan3_k<<<NPARTS, 256, 0, stream>>>(rowptr, pscan, widx);
    fill_k<<<(N_EDGES + 255) / 256, 256, 0, stream>>>(edge_index, widx, adj);

    // layer 1
    gemm_k<<<NPAD / 64, 256, 0, stream>>>(emb_bf, BT1, H);
    agg1_k<<<NPAD / 2, 256, 0, stream>>>(H, rowptr, adj, b1, x1);

    // layer 2
    gemm_k<<<NPAD / 64, 256, 0, stream>>>(x1, BT2, H);
    agg2_k<<<N_NODES / 2, 256, 0, stream>>>(H, rowptr, adj, b2, Wlin, p, q);

    // link predictor
    out_k<<<(N_LABELS + 255) / 256, 256, 0, stream>>>(eli, p, q, blin, out);
}

// Round 2
// 376.238 us; speedup vs baseline: 1.5551x; 1.5551x over previous
//
#include <hip/hip_runtime.h>
#include <hip/hip_bf16.h>

#define N_NODES 100000
#define N_EDGES 600000
#define N_LABELS 200000
#define DIM 128
#define NPAD 100032          // 1563 * 64  (GEMM row-tile padding)
#define NPARTS 391           // ceil(N_NODES/256)

using short8 = __attribute__((ext_vector_type(8))) short;
using f32x4  = __attribute__((ext_vector_type(4))) float;

__device__ __forceinline__ float b2f(short s) {
    union { unsigned u; float f; } c;
    c.u = ((unsigned)(unsigned short)s) << 16;
    return c.f;
}
__device__ __forceinline__ short f2b(float f) {
    __hip_bfloat16 h = __float2bfloat16(f);
    return *reinterpret_cast<short*>(&h);
}

// ---------------- weight conversion: build BT1/BT2 (256 x 128, row-major in K) ----------------
// cols 0..127 = Wl, 128..255 = Wr
__global__ void convert_w_k(const float* __restrict__ W1l, const float* __restrict__ W1r,
                            const float* __restrict__ W2l, const float* __restrict__ W2r,
                            short* __restrict__ BT1, short* __restrict__ BT2) {
    int i = blockIdx.x * 256 + threadIdx.x;     // 65536 threads
    int which = i >> 15;
    int r = i & 32767;
    int n = r >> 7;
    int k = r & 127;
    const float* Wl = which ? W2l : W1l;
    const float* Wr = which ? W2r : W1r;
    short* BT = which ? BT2 : BT1;
    float v = (n < 128) ? Wl[k * 128 + n] : Wr[k * 128 + (n - 128)];
    BT[n * 128 + k] = f2b(v);
}

// ---------------- CSR build ----------------

__global__ void count_k(const int* __restrict__ ei, int* __restrict__ cnt) {
    int e = blockIdx.x * blockDim.x + threadIdx.x;
    if (e < N_EDGES) atomicAdd(&cnt[ei[N_EDGES + e]], 1);
}

__global__ void scan1_k(const int* __restrict__ cnt, int* __restrict__ rowptr,
                        int* __restrict__ partials) {
    __shared__ int s[256];
    int t = threadIdx.x;
    int i = blockIdx.x * 256 + t;
    int v = (i < N_NODES) ? cnt[i] : 0;
    s[t] = v;
    __syncthreads();
    for (int off = 1; off < 256; off <<= 1) {
        int x = s[t];
        int y = (t >= off) ? s[t - off] : 0;
        __syncthreads();
        s[t] = x + y;
        __syncthreads();
    }
    if (i < N_NODES) rowptr[i] = s[t] - v;      // block-local exclusive
    if (t == 255) partials[blockIdx.x] = s[255];
}

__global__ void scan2_k(const int* __restrict__ partials, int* __restrict__ pscan,
                        int* __restrict__ rowptr) {
    __shared__ int s[512];
    int t = threadIdx.x;
    int v = (t < NPARTS) ? partials[t] : 0;
    s[t] = v;
    __syncthreads();
    for (int off = 1; off < 512; off <<= 1) {
        int x = s[t];
        int y = (t >= off) ? s[t - off] : 0;
        __syncthreads();
        s[t] = x + y;
        __syncthreads();
    }
    if (t < NPARTS) pscan[t] = s[t] - v;        // exclusive across blocks
    if (t == 511) rowptr[N_NODES] = s[511];     // total = N_EDGES
}

__global__ void scan3_k(int* __restrict__ rowptr, const int* __restrict__ pscan,
                        int* __restrict__ widx) {
    int i = blockIdx.x * 256 + threadIdx.x;
    if (i < N_NODES) {
        int v = rowptr[i] + pscan[i >> 8];
        rowptr[i] = v;
        widx[i] = v;
    }
}

__global__ void fill_k(const int* __restrict__ ei, int* __restrict__ widx,
                       int* __restrict__ adj) {
    int e = blockIdx.x * blockDim.x + threadIdx.x;
    if (e < N_EDGES) {
        int d = ei[N_EDGES + e];
        int pos = atomicAdd(&widx[d], 1);
        adj[pos] = ei[e];
    }
}

// ---------------- GEMM: [Hl|Hr][NPAD x 128 each] = A[NPAD x 128] @ [Wl|Wr]  (bf16 MFMA) ----------------
// F32A: A is float32 with N_NODES valid rows (emb); else A is bf16 with NPAD rows (x1, pad-zeroed).

template <bool F32A>
__global__ __launch_bounds__(256) void gemm_k(const void* __restrict__ Av,
                                              const short* __restrict__ BT,
                                              short* __restrict__ Hl,
                                              short* __restrict__ Hr) {
    int lane = threadIdx.x & 63;
    int wave = threadIdx.x >> 6;
    int quad = lane >> 4;
    int l16  = lane & 15;
    long rowbase = (long)blockIdx.x * 64 + wave * 16;
    long arow = rowbase + l16;

    f32x4 acc[16];
#pragma unroll
    for (int t = 0; t < 16; ++t)
#pragma unroll
        for (int r = 0; r < 4; ++r) acc[t][r] = 0.f;

#pragma unroll
    for (int kk = 0; kk < 4; ++kk) {
        short8 a;
        if (F32A) {
            const float* Af = (const float*)Av;
            if (arow < N_NODES) {
                f32x4 a0 = *(const f32x4*)(Af + arow * DIM + kk * 32 + quad * 8);
                f32x4 a1 = *(const f32x4*)(Af + arow * DIM + kk * 32 + quad * 8 + 4);
#pragma unroll
                for (int j = 0; j < 4; ++j) { a[j] = f2b(a0[j]); a[4 + j] = f2b(a1[j]); }
            } else {
#pragma unroll
                for (int j = 0; j < 8; ++j) a[j] = 0;
            }
        } else {
            const short* Ax = (const short*)Av;
            a = *(const short8*)(Ax + arow * DIM + kk * 32 + quad * 8);
        }
#pragma unroll
        for (int t = 0; t < 16; ++t) {
            short8 b = *(const short8*)(BT + (t * 16 + l16) * DIM + kk * 32 + quad * 8);
            acc[t] = __builtin_amdgcn_mfma_f32_16x16x32_bf16(a, b, acc[t], 0, 0, 0);
        }
    }

    // C/D layout: row = quad*4 + r, col = l16
#pragma unroll
    for (int t = 0; t < 16; ++t)
#pragma unroll
        for (int r = 0; r < 4; ++r) {
            long row = rowbase + quad * 4 + r;
            if (t < 8) Hl[row * DIM + t * 16 + l16]       = f2b(acc[t][r]);
            else       Hr[row * DIM + (t - 8) * 16 + l16] = f2b(acc[t][r]);
        }
}

// ---------------- gather-mean: one wave per node, 4 edges per load, 16B/lane ----------------

__device__ __forceinline__ void gather_mean(const short* __restrict__ Hl,
                                            const int* __restrict__ rowptr,
                                            const int* __restrict__ adj,
                                            int node, int lane, float sum[8], float& inv) {
    int g  = lane >> 4;
    int f0 = (lane & 15) << 3;
    int beg = rowptr[node];
    int deg = rowptr[node + 1] - beg;
#pragma unroll
    for (int j = 0; j < 8; ++j) sum[j] = 0.f;

    int av = (lane < deg) ? adj[beg + lane] : 0;
    int degc = deg < 64 ? deg : 64;

    // software-pipelined: one group of 4 edges in flight
    short8 h0;
    bool v0 = false;
    if (degc > 0) {
        int idx = __shfl(av, g, 64);
        v0 = g < degc;
        if (v0) h0 = *(const short8*)(Hl + (long)idx * DIM + f0);
    }
    for (int e0 = 4; e0 < degc; e0 += 4) {
        int idx = __shfl(av, e0 + g, 64);
        bool v1 = (e0 + g) < degc;
        short8 h1;
        if (v1) h1 = *(const short8*)(Hl + (long)idx * DIM + f0);
        if (v0) {
#pragma unroll
            for (int j = 0; j < 8; ++j) sum[j] += b2f(h0[j]);
        }
        h0 = h1; v0 = v1;
    }
    if (v0) {
#pragma unroll
        for (int j = 0; j < 8; ++j) sum[j] += b2f(h0[j]);
    }
    // rare fallback: degree > 64
    for (int e0 = 64; e0 < deg; e0 += 4) {
        int e = e0 + g;
        if (e < deg) {
            int idx = adj[beg + e];
            short8 h = *(const short8*)(Hl + (long)idx * DIM + f0);
#pragma unroll
            for (int j = 0; j < 8; ++j) sum[j] += b2f(h[j]);
        }
    }
    // reduce across the 4 edge-slots (lanes xor 16, 32)
#pragma unroll
    for (int j = 0; j < 8; ++j) {
        sum[j] += __shfl_xor(sum[j], 16, 64);
        sum[j] += __shfl_xor(sum[j], 32, 64);
    }
    inv = deg > 0 ? 1.f / (float)deg : 0.f;
}

// layer-1: x1 = relu(mean(Hl[nbrs]) + Hr + b1), bf16 out, pads zeroed
__global__ void agg1_k(const short* __restrict__ Hl, const short* __restrict__ Hr,
                       const int* __restrict__ rowptr, const int* __restrict__ adj,
                       const float* __restrict__ b1, short* __restrict__ x1) {
    int lane = threadIdx.x & 63;
    int node = blockIdx.x * 4 + (threadIdx.x >> 6);
    int g  = lane >> 4;
    int f0 = (lane & 15) << 3;

    if (node >= N_NODES) {
        if (node < NPAD && g == 0) {
            short8 z;
#pragma unroll
            for (int j = 0; j < 8; ++j) z[j] = 0;
            *(short8*)(x1 + (long)node * DIM + f0) = z;
        }
        return;
    }
    float sum[8]; float inv;
    gather_mean(Hl, rowptr, adj, node, lane, sum, inv);

    f32x4 bb0 = *(const f32x4*)(b1 + f0);
    f32x4 bb1 = *(const f32x4*)(b1 + f0 + 4);
    short8 hr = *(const short8*)(Hr + (long)node * DIM + f0);
    short8 o;
#pragma unroll
    for (int j = 0; j < 8; ++j) {
        float bias = (j < 4) ? bb0[j] : bb1[j - 4];
        float v = sum[j] * inv + b2f(hr[j]) + bias;
        o[j] = f2b(fmaxf(v, 0.f));
    }
    if (g == 0) *(short8*)(x1 + (long)node * DIM + f0) = o;
}

// layer-2 fused with link-predictor projections: p = x2 . Wlin[:128], q = x2 . Wlin[128:]
__global__ void agg2_k(const short* __restrict__ Hl, const short* __restrict__ Hr,
                       const int* __restrict__ rowptr, const int* __restrict__ adj,
                       const float* __restrict__ b2, const float* __restrict__ Wlin,
                       float* __restrict__ p, float* __restrict__ q) {
    int lane = threadIdx.x & 63;
    int node = blockIdx.x * 4 + (threadIdx.x >> 6);
    int f0 = (lane & 15) << 3;

    float sum[8]; float inv;
    gather_mean(Hl, rowptr, adj, node, lane, sum, inv);

    f32x4 bb0 = *(const f32x4*)(b2 + f0);
    f32x4 bb1 = *(const f32x4*)(b2 + f0 + 4);
    f32x4 w0  = *(const f32x4*)(Wlin + f0);
    f32x4 w1  = *(const f32x4*)(Wlin + f0 + 4);
    f32x4 w2  = *(const f32x4*)(Wlin + 128 + f0);
    f32x4 w3  = *(const f32x4*)(Wlin + 128 + f0 + 4);
    short8 hr = *(const short8*)(Hr + (long)node * DIM + f0);
    float pp = 0.f, qq = 0.f;
#pragma unroll
    for (int j = 0; j < 8; ++j) {
        float bias = (j < 4) ? bb0[j] : bb1[j - 4];
        float v = sum[j] * inv + b2f(hr[j]) + bias;
        float wp = (j < 4) ? w0[j] : w1[j - 4];
        float wq = (j < 4) ? w2[j] : w3[j - 4];
        pp += v * wp;
        qq += v * wq;
    }
    // reduce across 16 feature-group lanes (within each 16-lane group)
#pragma unroll
    for (int m = 1; m <= 8; m <<= 1) {
        pp += __shfl_xor(pp, m, 64);
        qq += __shfl_xor(qq, m, 64);
    }
    if (lane == 0) { p[node] = pp; q[node] = qq; }
}

__global__ void out_k(const int* __restrict__ eli, const float* __restrict__ p,
                      const float* __restrict__ q, const float* __restrict__ blin,
                      float* __restrict__ out) {
    int i = blockIdx.x * blockDim.x + threadIdx.x;
    if (i < N_LABELS) out[i] = p[eli[i]] + q[eli[N_LABELS + i]] + blin[0];
}

// ---------------- launch ----------------

extern "C" void kernel_launch(void* const* d_in, const int* in_sizes, int n_in,
                              void* d_out, int out_size, void* d_ws, size_t ws_size,
                              hipStream_t stream) {
    const int*   edge_index = (const int*)d_in[0];
    const int*   eli        = (const int*)d_in[1];
    const float* emb        = (const float*)d_in[2];
    const float* W1l        = (const float*)d_in[3];
    const float* b1         = (const float*)d_in[4];
    const float* W1r        = (const float*)d_in[5];
    const float* W2l        = (const float*)d_in[6];
    const float* b2         = (const float*)d_in[7];
    const float* W2r        = (const float*)d_in[8];
    const float* Wlin       = (const float*)d_in[9];
    const float* blin       = (const float*)d_in[10];
    float* out = (float*)d_out;

    char* ws = (char*)d_ws;
    size_t off = 0;
    auto alloc = [&](size_t bytes) -> void* {
        off = (off + 255) & ~(size_t)255;
        void* ptr = ws + off;
        off += bytes;
        return ptr;
    };

    short* Hl  = (short*)alloc((size_t)NPAD * DIM * 2);
    short* Hr  = (short*)alloc((size_t)NPAD * DIM * 2);
    short* x1  = (short*)alloc((size_t)NPAD * DIM * 2);
    short* BT1 = (short*)alloc(256 * 128 * 2);
    short* BT2 = (short*)alloc(256 * 128 * 2);
    int* cnt      = (int*)alloc((size_t)N_NODES * 4);
    int* rowptr   = (int*)alloc((size_t)(N_NODES + 1) * 4);
    int* widx     = (int*)alloc((size_t)N_NODES * 4);
    int* adj      = (int*)alloc((size_t)N_EDGES * 4);
    int* partials = (int*)alloc(NPARTS * 4);
    int* pscan    = (int*)alloc(NPARTS * 4);
    float* p      = (float*)alloc((size_t)N_NODES * 4);
    float* q      = (float*)alloc((size_t)N_NODES * 4);

    hipMemsetAsync(cnt, 0, (size_t)N_NODES * 4, stream);

    convert_w_k<<<256, 256, 0, stream>>>(W1l, W1r, W2l, W2r, BT1, BT2);

    // CSR build
    count_k<<<(N_EDGES + 255) / 256, 256, 0, stream>>>(edge_index, cnt);
    scan1_k<<<NPARTS, 256, 0, stream>>>(cnt, rowptr, partials);
    scan2_k<<<1, 512, 0, stream>>>(partials, pscan, rowptr);
    scan3_k<<<NPARTS, 256, 0, stream>>>(rowptr, pscan, widx);
    fill_k<<<(N_EDGES + 255) / 256, 256, 0, stream>>>(edge_index, widx, adj);

    // layer 1 (emb f32 read + convert fused into GEMM)
    gemm_k<true><<<NPAD / 64, 256, 0, stream>>>(emb, BT1, Hl, Hr);
    agg1_k<<<NPAD / 4, 256, 0, stream>>>(Hl, Hr, rowptr, adj, b1, x1);

    // layer 2
    gemm_k<false><<<NPAD / 64, 256, 0, stream>>>(x1, BT2, Hl, Hr);
    agg2_k<<<N_NODES / 4, 256, 0, stream>>>(Hl, Hr, rowptr, adj, b2, Wlin, p, q);

    // link predictor
    out_k<<<(N_LABELS + 255) / 256, 256, 0, stream>>>(eli, p, q, blin, out);
}

// Round 3
// 310.422 us; speedup vs baseline: 1.8849x; 1.2120x over previous
//
#include <hip/hip_runtime.h>
#include <hip/hip_bf16.h>

#define N_NODES 100000
#define N_EDGES 600000
#define N_LABELS 200000
#define DIM 128
#define NPAD 100032          // 1563 * 64  (GEMM row-tile padding)
#define NPARTS 391           // ceil(N_NODES/256)

using short4v = __attribute__((ext_vector_type(4))) short;
using short8 = __attribute__((ext_vector_type(8))) short;
using f32x4  = __attribute__((ext_vector_type(4))) float;

__device__ __forceinline__ float b2f(short s) {
    union { unsigned u; float f; } c;
    c.u = ((unsigned)(unsigned short)s) << 16;
    return c.f;
}
__device__ __forceinline__ short f2b(float f) {
    __hip_bfloat16 h = __float2bfloat16(f);
    return *reinterpret_cast<short*>(&h);
}

// ---------------- weight conversion: build BT1/BT2 (256 x 128, row-major in K) ----------------
// rows (n) 0..127 = Wl cols, 128..255 = Wr cols
__global__ void convert_w_k(const float* __restrict__ W1l, const float* __restrict__ W1r,
                            const float* __restrict__ W2l, const float* __restrict__ W2r,
                            short* __restrict__ BT1, short* __restrict__ BT2) {
    int i = blockIdx.x * 256 + threadIdx.x;     // 65536 threads
    int which = i >> 15;
    int r = i & 32767;
    int n = r >> 7;
    int k = r & 127;
    const float* Wl = which ? W2l : W1l;
    const float* Wr = which ? W2r : W1r;
    short* BT = which ? BT2 : BT1;
    float v = (n < 128) ? Wl[k * 128 + n] : Wr[k * 128 + (n - 128)];
    BT[n * 128 + k] = f2b(v);
}

// ---------------- CSR build ----------------

__global__ void count_k(const int* __restrict__ ei, int* __restrict__ cnt) {
    int e = blockIdx.x * blockDim.x + threadIdx.x;
    if (e < N_EDGES) atomicAdd(&cnt[ei[N_EDGES + e]], 1);
}

__global__ void scan1_k(const int* __restrict__ cnt, int* __restrict__ rowptr,
                        int* __restrict__ partials) {
    __shared__ int s[256];
    int t = threadIdx.x;
    int i = blockIdx.x * 256 + t;
    int v = (i < N_NODES) ? cnt[i] : 0;
    s[t] = v;
    __syncthreads();
    for (int off = 1; off < 256; off <<= 1) {
        int x = s[t];
        int y = (t >= off) ? s[t - off] : 0;
        __syncthreads();
        s[t] = x + y;
        __syncthreads();
    }
    if (i < N_NODES) rowptr[i] = s[t] - v;      // block-local exclusive
    if (t == 255) partials[blockIdx.x] = s[255];
}

__global__ void scan2_k(const int* __restrict__ partials, int* __restrict__ pscan,
                        int* __restrict__ rowptr) {
    __shared__ int s[512];
    int t = threadIdx.x;
    int v = (t < NPARTS) ? partials[t] : 0;
    s[t] = v;
    __syncthreads();
    for (int off = 1; off < 512; off <<= 1) {
        int x = s[t];
        int y = (t >= off) ? s[t - off] : 0;
        __syncthreads();
        s[t] = x + y;
        __syncthreads();
    }
    if (t < NPARTS) pscan[t] = s[t] - v;        // exclusive across blocks
    if (t == 511) rowptr[N_NODES] = s[511];     // total = N_EDGES
}

__global__ void scan3_k(int* __restrict__ rowptr, const int* __restrict__ pscan,
                        int* __restrict__ widx) {
    int i = blockIdx.x * 256 + threadIdx.x;
    if (i < N_NODES) {
        int v = rowptr[i] + pscan[i >> 8];
        rowptr[i] = v;
        widx[i] = v;
    }
}

__global__ void fill_k(const int* __restrict__ ei, int* __restrict__ widx,
                       int* __restrict__ adj) {
    int e = blockIdx.x * blockDim.x + threadIdx.x;
    if (e < N_EDGES) {
        int d = ei[N_EDGES + e];
        int pos = atomicAdd(&widx[d], 1);
        adj[pos] = ei[e];
    }
}

// ---------------- GEMM: [Hl|Hr][NPAD x 128 each] = A[NPAD x 128] @ [Wl|Wr]  (bf16 MFMA) ----------------
// Weight-resident, operand-swapped: A_op = weight frags (m = out feature), B_op = node rows (n = node).
// D lane layout: feature = quad*4+r (4 consecutive per lane!), node = l16 -> 8B packed stores.
// Each wave owns one 128-feature half (Hl or Hr); wave-pairs share node tiles for L1 reuse.
// F32A: A is float32 with N_NODES valid rows (emb); else A is bf16 with NPAD rows (x1, pad-zeroed).

#define GEMM_GRID 512

template <bool F32A>
__global__ __launch_bounds__(256, 2) void gemm_k(const void* __restrict__ Av,
                                                 const short* __restrict__ BT,
                                                 short* __restrict__ Hl,
                                                 short* __restrict__ Hr) {
    int lane = threadIdx.x & 63;
    int wave = threadIdx.x >> 6;
    int quad = lane >> 4;
    int l16  = lane & 15;
    int half = wave & 1;
    int pair = blockIdx.x * 2 + (wave >> 1);
    const int NT = NPAD / 16;
    const int P  = GEMM_GRID * 2;

    short* __restrict__ H = half ? Hr : Hl;

    // resident weight fragments: Wf[t][kk] = BT[half*128 + t*16 + l16][kk*32 + quad*8 + j]
    short8 Wf[8][4];
#pragma unroll
    for (int t = 0; t < 8; ++t)
#pragma unroll
        for (int kk = 0; kk < 4; ++kk)
            Wf[t][kk] = *(const short8*)(BT + (half * 128 + t * 16 + l16) * DIM + kk * 32 + quad * 8);

    for (int s = pair; s < NT; s += P) {
        long arow = (long)s * 16 + l16;

        // node-row fragments: xf[kk] = A[arow][kk*32 + quad*8 + j]
        short8 xf[4];
        if (F32A) {
            const float* Af = (const float*)Av;
            if (arow < N_NODES) {
#pragma unroll
                for (int kk = 0; kk < 4; ++kk) {
                    f32x4 a0 = *(const f32x4*)(Af + arow * DIM + kk * 32 + quad * 8);
                    f32x4 a1 = *(const f32x4*)(Af + arow * DIM + kk * 32 + quad * 8 + 4);
#pragma unroll
                    for (int j = 0; j < 4; ++j) { xf[kk][j] = f2b(a0[j]); xf[kk][4 + j] = f2b(a1[j]); }
                }
            } else {
#pragma unroll
                for (int kk = 0; kk < 4; ++kk)
#pragma unroll
                    for (int j = 0; j < 8; ++j) xf[kk][j] = 0;
            }
        } else {
            const short* Ax = (const short*)Av;
#pragma unroll
            for (int kk = 0; kk < 4; ++kk)
                xf[kk] = *(const short8*)(Ax + arow * DIM + kk * 32 + quad * 8);
        }

        f32x4 acc[8];
#pragma unroll
        for (int t = 0; t < 8; ++t)
#pragma unroll
            for (int r = 0; r < 4; ++r) acc[t][r] = 0.f;

#pragma unroll
        for (int kk = 0; kk < 4; ++kk)
#pragma unroll
            for (int t = 0; t < 8; ++t)
                acc[t] = __builtin_amdgcn_mfma_f32_16x16x32_bf16(Wf[t][kk], xf[kk], acc[t], 0, 0, 0);

        // store: lane holds node=arow, features t*16 + quad*4 + {0..3} -> one 8B store per t
#pragma unroll
        for (int t = 0; t < 8; ++t) {
            short4v o;
#pragma unroll
            for (int r = 0; r < 4; ++r) o[r] = f2b(acc[t][r]);
            *(short4v*)(H + arow * DIM + t * 16 + quad * 4) = o;
        }
    }
}

// ---------------- gather-mean: one wave per node, 4 edges per load, 16B/lane ----------------

__device__ __forceinline__ void gather_mean(const short* __restrict__ Hl,
                                            const int* __restrict__ rowptr,
                                            const int* __restrict__ adj,
                                            int node, int lane, float sum[8], float& inv) {
    int g  = lane >> 4;
    int f0 = (lane & 15) << 3;
    int beg = rowptr[node];
    int deg = rowptr[node + 1] - beg;
#pragma unroll
    for (int j = 0; j < 8; ++j) sum[j] = 0.f;

    int av = (lane < deg) ? adj[beg + lane] : 0;
    int degc = deg < 64 ? deg : 64;

    // software-pipelined: one group of 4 edges in flight
    short8 h0;
    bool v0 = false;
    if (degc > 0) {
        int idx = __shfl(av, g, 64);
        v0 = g < degc;
        if (v0) h0 = *(const short8*)(Hl + (long)idx * DIM + f0);
    }
    for (int e0 = 4; e0 < degc; e0 += 4) {
        int idx = __shfl(av, e0 + g, 64);
        bool v1 = (e0 + g) < degc;
        short8 h1;
        if (v1) h1 = *(const short8*)(Hl + (long)idx * DIM + f0);
        if (v0) {
#pragma unroll
            for (int j = 0; j < 8; ++j) sum[j] += b2f(h0[j]);
        }
        h0 = h1; v0 = v1;
    }
    if (v0) {
#pragma unroll
        for (int j = 0; j < 8; ++j) sum[j] += b2f(h0[j]);
    }
    // rare fallback: degree > 64
    for (int e0 = 64; e0 < deg; e0 += 4) {
        int e = e0 + g;
        if (e < deg) {
            int idx = adj[beg + e];
            short8 h = *(const short8*)(Hl + (long)idx * DIM + f0);
#pragma unroll
            for (int j = 0; j < 8; ++j) sum[j] += b2f(h[j]);
        }
    }
    // reduce across the 4 edge-slots (lanes xor 16, 32)
#pragma unroll
    for (int j = 0; j < 8; ++j) {
        sum[j] += __shfl_xor(sum[j], 16, 64);
        sum[j] += __shfl_xor(sum[j], 32, 64);
    }
    inv = deg > 0 ? 1.f / (float)deg : 0.f;
}

// layer-1: x1 = relu(mean(Hl[nbrs]) + Hr + b1), bf16 out, pads zeroed
__global__ void agg1_k(const short* __restrict__ Hl, const short* __restrict__ Hr,
                       const int* __restrict__ rowptr, const int* __restrict__ adj,
                       const float* __restrict__ b1, short* __restrict__ x1) {
    int lane = threadIdx.x & 63;
    int node = blockIdx.x * 4 + (threadIdx.x >> 6);
    int g  = lane >> 4;
    int f0 = (lane & 15) << 3;

    if (node >= N_NODES) {
        if (node < NPAD && g == 0) {
            short8 z;
#pragma unroll
            for (int j = 0; j < 8; ++j) z[j] = 0;
            *(short8*)(x1 + (long)node * DIM + f0) = z;
        }
        return;
    }
    float sum[8]; float inv;
    gather_mean(Hl, rowptr, adj, node, lane, sum, inv);

    f32x4 bb0 = *(const f32x4*)(b1 + f0);
    f32x4 bb1 = *(const f32x4*)(b1 + f0 + 4);
    short8 hr = *(const short8*)(Hr + (long)node * DIM + f0);
    short8 o;
#pragma unroll
    for (int j = 0; j < 8; ++j) {
        float bias = (j < 4) ? bb0[j] : bb1[j - 4];
        float v = sum[j] * inv + b2f(hr[j]) + bias;
        o[j] = f2b(fmaxf(v, 0.f));
    }
    if (g == 0) *(short8*)(x1 + (long)node * DIM + f0) = o;
}

// layer-2 fused with link-predictor projections: p = x2 . Wlin[:128], q = x2 . Wlin[128:]
__global__ void agg2_k(const short* __restrict__ Hl, const short* __restrict__ Hr,
                       const int* __restrict__ rowptr, const int* __restrict__ adj,
                       const float* __restrict__ b2, const float* __restrict__ Wlin,
                       float* __restrict__ p, float* __restrict__ q) {
    int lane = threadIdx.x & 63;
    int node = blockIdx.x * 4 + (threadIdx.x >> 6);
    int f0 = (lane & 15) << 3;

    float sum[8]; float inv;
    gather_mean(Hl, rowptr, adj, node, lane, sum, inv);

    f32x4 bb0 = *(const f32x4*)(b2 + f0);
    f32x4 bb1 = *(const f32x4*)(b2 + f0 + 4);
    f32x4 w0  = *(const f32x4*)(Wlin + f0);
    f32x4 w1  = *(const f32x4*)(Wlin + f0 + 4);
    f32x4 w2  = *(const f32x4*)(Wlin + 128 + f0);
    f32x4 w3  = *(const f32x4*)(Wlin + 128 + f0 + 4);
    short8 hr = *(const short8*)(Hr + (long)node * DIM + f0);
    float pp = 0.f, qq = 0.f;
#pragma unroll
    for (int j = 0; j < 8; ++j) {
        float bias = (j < 4) ? bb0[j] : bb1[j - 4];
        float v = sum[j] * inv + b2f(hr[j]) + bias;
        float wp = (j < 4) ? w0[j] : w1[j - 4];
        float wq = (j < 4) ? w2[j] : w3[j - 4];
        pp += v * wp;
        qq += v * wq;
    }
    // reduce across 16 feature-group lanes (within each 16-lane group)
#pragma unroll
    for (int m = 1; m <= 8; m <<= 1) {
        pp += __shfl_xor(pp, m, 64);
        qq += __shfl_xor(qq, m, 64);
    }
    if (lane == 0) { p[node] = pp; q[node] = qq; }
}

__global__ void out_k(const int* __restrict__ eli, const float* __restrict__ p,
                      const float* __restrict__ q, const float* __restrict__ blin,
                      float* __restrict__ out) {
    int i = blockIdx.x * blockDim.x + threadIdx.x;
    if (i < N_LABELS) out[i] = p[eli[i]] + q[eli[N_LABELS + i]] + blin[0];
}

// ---------------- launch ----------------

extern "C" void kernel_launch(void* const* d_in, const int* in_sizes, int n_in,
                              void* d_out, int out_size, void* d_ws, size_t ws_size,
                              hipStream_t stream) {
    const int*   edge_index = (const int*)d_in[0];
    const int*   eli        = (const int*)d_in[1];
    const float* emb        = (const float*)d_in[2];
    const float* W1l        = (const float*)d_in[3];
    const float* b1         = (const float*)d_in[4];
    const float* W1r        = (const float*)d_in[5];
    const float* W2l        = (const float*)d_in[6];
    const float* b2         = (const float*)d_in[7];
    const float* W2r        = (const float*)d_in[8];
    const float* Wlin       = (const float*)d_in[9];
    const float* blin       = (const float*)d_in[10];
    float* out = (float*)d_out;

    char* ws = (char*)d_ws;
    size_t off = 0;
    auto alloc = [&](size_t bytes) -> void* {
        off = (off + 255) & ~(size_t)255;
        void* ptr = ws + off;
        off += bytes;
        return ptr;
    };

    short* Hl  = (short*)alloc((size_t)NPAD * DIM * 2);
    short* Hr  = (short*)alloc((size_t)NPAD * DIM * 2);
    short* x1  = (short*)alloc((size_t)NPAD * DIM * 2);
    short* BT1 = (short*)alloc(256 * 128 * 2);
    short* BT2 = (short*)alloc(256 * 128 * 2);
    int* cnt      = (int*)alloc((size_t)N_NODES * 4);
    int* rowptr   = (int*)alloc((size_t)(N_NODES + 1) * 4);
    int* widx     = (int*)alloc((size_t)N_NODES * 4);
    int* adj      = (int*)alloc((size_t)N_EDGES * 4);
    int* partials = (int*)alloc(NPARTS * 4);
    int* pscan    = (int*)alloc(NPARTS * 4);
    float* p      = (float*)alloc((size_t)N_NODES * 4);
    float* q      = (float*)alloc((size_t)N_NODES * 4);

    hipMemsetAsync(cnt, 0, (size_t)N_NODES * 4, stream);

    convert_w_k<<<256, 256, 0, stream>>>(W1l, W1r, W2l, W2r, BT1, BT2);

    // CSR build
    count_k<<<(N_EDGES + 255) / 256, 256, 0, stream>>>(edge_index, cnt);
    scan1_k<<<NPARTS, 256, 0, stream>>>(cnt, rowptr, partials);
    scan2_k<<<1, 512, 0, stream>>>(partials, pscan, rowptr);
    scan3_k<<<NPARTS, 256, 0, stream>>>(rowptr, pscan, widx);
    fill_k<<<(N_EDGES + 255) / 256, 256, 0, stream>>>(edge_index, widx, adj);

    // layer 1 (emb f32 read + convert fused into GEMM)
    gemm_k<true><<<GEMM_GRID, 256, 0, stream>>>(emb, BT1, Hl, Hr);
    agg1_k<<<NPAD / 4, 256, 0, stream>>>(Hl, Hr, rowptr, adj, b1, x1);

    // layer 2
    gemm_k<false><<<GEMM_GRID, 256, 0, stream>>>(x1, BT2, Hl, Hr);
    agg2_k<<<N_NODES / 4, 256, 0, stream>>>(Hl, Hr, rowptr, adj, b2, Wlin, p, q);

    // link predictor
    out_k<<<(N_LABELS + 255) / 256, 256, 0, stream>>>(eli, p, q, blin, out);
}

// Round 4
// 271.295 us; speedup vs baseline: 2.1567x; 1.1442x over previous
//
#include <hip/hip_runtime.h>
#include <hip/hip_bf16.h>

#define N_NODES 100000
#define N_EDGES 600000
#define N_LABELS 200000
#define DIM 128
#define NPARTS 391           // ceil(N_NODES/256)
#define NT_TILES 6250        // N_NODES / 16 exactly
#define GEMM_GRID 512

using short4v = __attribute__((ext_vector_type(4))) short;
using short8 = __attribute__((ext_vector_type(8))) short;
using f32x4  = __attribute__((ext_vector_type(4))) float;

__device__ __forceinline__ float b2f(short s) {
    union { unsigned u; float f; } c;
    c.u = ((unsigned)(unsigned short)s) << 16;
    return c.f;
}
__device__ __forceinline__ short f2b(float f) {
    __hip_bfloat16 h = __float2bfloat16(f);
    return *reinterpret_cast<short*>(&h);
}

// ---------------- prep: BT1 (bf16, 256x128 K-major) + u/v projection vectors + c consts ----------
// u_p = W2l @ Wlin[:128], u_q = W2l @ Wlin[128:], v_p = W2r @ wp, v_q = W2r @ wq,
// c = (b2.wp, b2.wq).  p[n] = mean_nbrs(x1.u_p) + x1[n].v_p + c.x
__global__ void prep_k(const float* __restrict__ W1l, const float* __restrict__ W1r,
                       short* __restrict__ BT1,
                       const float* __restrict__ W2l, const float* __restrict__ W2r,
                       const float* __restrict__ Wlin, const float* __restrict__ b2,
                       float* __restrict__ up, float* __restrict__ uq,
                       float* __restrict__ vp, float* __restrict__ vq,
                       float2* __restrict__ cpq) {
    int b = blockIdx.x;
    int t = threadIdx.x;
    if (b < 128) {
        int i = b * 256 + t;                 // 32768 = 256 x 128
        int n = i >> 7, k = i & 127;
        float v = (n < 128) ? W1l[k * 128 + n] : W1r[k * 128 + (n - 128)];
        BT1[n * 128 + k] = f2b(v);
    } else if (b == 128) {
        const float* W = (t < 128) ? W2l : W2r;
        int k = t & 127;
        float s0 = 0.f, s1 = 0.f;
        for (int n = 0; n < 128; ++n) {
            float w = W[k * 128 + n];
            s0 += w * Wlin[n];
            s1 += w * Wlin[128 + n];
        }
        if (t < 128) { up[k] = s0; uq[k] = s1; }
        else         { vp[k] = s0; vq[k] = s1; }
    } else {
        if (t < 64) {
            float p0 = b2[t] * Wlin[t] + b2[t + 64] * Wlin[t + 64];
            float q0 = b2[t] * Wlin[128 + t] + b2[t + 64] * Wlin[192 + t];
#pragma unroll
            for (int m = 1; m <= 32; m <<= 1) {
                p0 += __shfl_xor(p0, m, 64);
                q0 += __shfl_xor(q0, m, 64);
            }
            if (t == 0) *cpq = make_float2(p0, q0);
        }
    }
}

// ---------------- CSR build ----------------

__global__ void count_k(const int* __restrict__ ei, int* __restrict__ cnt) {
    int e = blockIdx.x * blockDim.x + threadIdx.x;
    if (e < N_EDGES) atomicAdd(&cnt[ei[N_EDGES + e]], 1);
}

__global__ void scan1_k(const int* __restrict__ cnt, int* __restrict__ rowptr,
                        int* __restrict__ partials) {
    __shared__ int s[256];
    int t = threadIdx.x;
    int i = blockIdx.x * 256 + t;
    int v = (i < N_NODES) ? cnt[i] : 0;
    s[t] = v;
    __syncthreads();
    for (int off = 1; off < 256; off <<= 1) {
        int x = s[t];
        int y = (t >= off) ? s[t - off] : 0;
        __syncthreads();
        s[t] = x + y;
        __syncthreads();
    }
    if (i < N_NODES) rowptr[i] = s[t] - v;
    if (t == 255) partials[blockIdx.x] = s[255];
}

__global__ void scan2_k(const int* __restrict__ partials, int* __restrict__ pscan,
                        int* __restrict__ rowptr) {
    __shared__ int s[512];
    int t = threadIdx.x;
    int v = (t < NPARTS) ? partials[t] : 0;
    s[t] = v;
    __syncthreads();
    for (int off = 1; off < 512; off <<= 1) {
        int x = s[t];
        int y = (t >= off) ? s[t - off] : 0;
        __syncthreads();
        s[t] = x + y;
        __syncthreads();
    }
    if (t < NPARTS) pscan[t] = s[t] - v;
    if (t == 511) rowptr[N_NODES] = s[511];
}

__global__ void scan3_k(int* __restrict__ rowptr, const int* __restrict__ pscan,
                        int* __restrict__ widx) {
    int i = blockIdx.x * 256 + threadIdx.x;
    if (i < N_NODES) {
        int v = rowptr[i] + pscan[i >> 8];
        rowptr[i] = v;
        widx[i] = v;
    }
}

__global__ void fill_k(const int* __restrict__ ei, int* __restrict__ widx,
                       int* __restrict__ adj) {
    int e = blockIdx.x * blockDim.x + threadIdx.x;
    if (e < N_EDGES) {
        int d = ei[N_EDGES + e];
        int pos = atomicAdd(&widx[d], 1);
        adj[pos] = ei[e];
    }
}

// ---------------- GEMM1: [Hl|Hr] = bf16(emb) @ [W1l|W1r]  (weight-resident MFMA) ----------------
// A_op = weight frags (m = out feature), B_op = node rows (n = node).
// D lane layout: feature = quad*4+r (4 consecutive), node = l16 -> 8B packed stores.

__global__ __launch_bounds__(256, 2) void gemm_k(const float* __restrict__ Af,
                                                 const short* __restrict__ BT,
                                                 short* __restrict__ Hl,
                                                 short* __restrict__ Hr) {
    int lane = threadIdx.x & 63;
    int wave = threadIdx.x >> 6;
    int quad = lane >> 4;
    int l16  = lane & 15;
    int half = wave & 1;
    int pair = blockIdx.x * 2 + (wave >> 1);
    const int P = GEMM_GRID * 2;

    short* __restrict__ H = half ? Hr : Hl;

    short8 Wf[8][4];
#pragma unroll
    for (int t = 0; t < 8; ++t)
#pragma unroll
        for (int kk = 0; kk < 4; ++kk)
            Wf[t][kk] = *(const short8*)(BT + (half * 128 + t * 16 + l16) * DIM + kk * 32 + quad * 8);

    for (int s = pair; s < NT_TILES; s += P) {
        long arow = (long)s * 16 + l16;

        short8 xf[4];
#pragma unroll
        for (int kk = 0; kk < 4; ++kk) {
            f32x4 a0 = *(const f32x4*)(Af + arow * DIM + kk * 32 + quad * 8);
            f32x4 a1 = *(const f32x4*)(Af + arow * DIM + kk * 32 + quad * 8 + 4);
#pragma unroll
            for (int j = 0; j < 4; ++j) { xf[kk][j] = f2b(a0[j]); xf[kk][4 + j] = f2b(a1[j]); }
        }

        f32x4 acc[8];
#pragma unroll
        for (int t = 0; t < 8; ++t)
#pragma unroll
            for (int r = 0; r < 4; ++r) acc[t][r] = 0.f;

#pragma unroll
        for (int kk = 0; kk < 4; ++kk)
#pragma unroll
            for (int t = 0; t < 8; ++t)
                acc[t] = __builtin_amdgcn_mfma_f32_16x16x32_bf16(Wf[t][kk], xf[kk], acc[t], 0, 0, 0);

#pragma unroll
        for (int t = 0; t < 8; ++t) {
            short4v o;
#pragma unroll
            for (int r = 0; r < 4; ++r) o[r] = f2b(acc[t][r]);
            *(short4v*)(H + arow * DIM + t * 16 + quad * 4) = o;
        }
    }
}

// ---------------- gather-mean: one wave per node, 4 edges per load, 16B/lane ----------------

__device__ __forceinline__ void gather_mean(const short* __restrict__ Hl,
                                            const int* __restrict__ rowptr,
                                            const int* __restrict__ adj,
                                            int node, int lane, float sum[8], float& inv) {
    int g  = lane >> 4;
    int f0 = (lane & 15) << 3;
    int beg = rowptr[node];
    int deg = rowptr[node + 1] - beg;
#pragma unroll
    for (int j = 0; j < 8; ++j) sum[j] = 0.f;

    int av = (lane < deg) ? adj[beg + lane] : 0;
    int degc = deg < 64 ? deg : 64;

    short8 h0;
    bool v0 = false;
    if (degc > 0) {
        int idx = __shfl(av, g, 64);
        v0 = g < degc;
        if (v0) h0 = *(const short8*)(Hl + (long)idx * DIM + f0);
    }
    for (int e0 = 4; e0 < degc; e0 += 4) {
        int idx = __shfl(av, e0 + g, 64);
        bool v1 = (e0 + g) < degc;
        short8 h1;
        if (v1) h1 = *(const short8*)(Hl + (long)idx * DIM + f0);
        if (v0) {
#pragma unroll
            for (int j = 0; j < 8; ++j) sum[j] += b2f(h0[j]);
        }
        h0 = h1; v0 = v1;
    }
    if (v0) {
#pragma unroll
        for (int j = 0; j < 8; ++j) sum[j] += b2f(h0[j]);
    }
    for (int e0 = 64; e0 < deg; e0 += 4) {
        int e = e0 + g;
        if (e < deg) {
            int idx = adj[beg + e];
            short8 h = *(const short8*)(Hl + (long)idx * DIM + f0);
#pragma unroll
            for (int j = 0; j < 8; ++j) sum[j] += b2f(h[j]);
        }
    }
#pragma unroll
    for (int j = 0; j < 8; ++j) {
        sum[j] += __shfl_xor(sum[j], 16, 64);
        sum[j] += __shfl_xor(sum[j], 32, 64);
    }
    inv = deg > 0 ? 1.f / (float)deg : 0.f;
}

// layer-1 agg fused with layer-2 projections:
// x1 = relu(mean(Hl[nbrs]) + Hr + b1)  (in registers, fp32)
// S[node] = (x1.u_p, x1.u_q)   -- gathered by layer-2
// T[node] = (x1.v_p, x1.v_q)   -- self term
__global__ void agg1_k(const short* __restrict__ Hl, const short* __restrict__ Hr,
                       const int* __restrict__ rowptr, const int* __restrict__ adj,
                       const float* __restrict__ b1,
                       const float* __restrict__ up, const float* __restrict__ uq,
                       const float* __restrict__ vp, const float* __restrict__ vq,
                       float2* __restrict__ S, float2* __restrict__ T) {
    int lane = threadIdx.x & 63;
    int node = blockIdx.x * 4 + (threadIdx.x >> 6);
    int f0 = (lane & 15) << 3;
    if (node >= N_NODES) return;

    float sum[8]; float inv;
    gather_mean(Hl, rowptr, adj, node, lane, sum, inv);

    f32x4 bb0 = *(const f32x4*)(b1 + f0);
    f32x4 bb1 = *(const f32x4*)(b1 + f0 + 4);
    short8 hr = *(const short8*)(Hr + (long)node * DIM + f0);
    float x[8];
#pragma unroll
    for (int j = 0; j < 8; ++j) {
        float bias = (j < 4) ? bb0[j] : bb1[j - 4];
        x[j] = fmaxf(sum[j] * inv + b2f(hr[j]) + bias, 0.f);
    }

    f32x4 up0 = *(const f32x4*)(up + f0), up1 = *(const f32x4*)(up + f0 + 4);
    f32x4 uq0 = *(const f32x4*)(uq + f0), uq1 = *(const f32x4*)(uq + f0 + 4);
    f32x4 vp0 = *(const f32x4*)(vp + f0), vp1 = *(const f32x4*)(vp + f0 + 4);
    f32x4 vq0 = *(const f32x4*)(vq + f0), vq1 = *(const f32x4*)(vq + f0 + 4);
    float ap = 0.f, aq = 0.f, tp = 0.f, tq = 0.f;
#pragma unroll
    for (int j = 0; j < 8; ++j) {
        float upj = (j < 4) ? up0[j] : up1[j - 4];
        float uqj = (j < 4) ? uq0[j] : uq1[j - 4];
        float vpj = (j < 4) ? vp0[j] : vp1[j - 4];
        float vqj = (j < 4) ? vq0[j] : vq1[j - 4];
        ap += x[j] * upj;
        aq += x[j] * uqj;
        tp += x[j] * vpj;
        tq += x[j] * vqj;
    }
#pragma unroll
    for (int m = 1; m <= 8; m <<= 1) {
        ap += __shfl_xor(ap, m, 64);
        aq += __shfl_xor(aq, m, 64);
        tp += __shfl_xor(tp, m, 64);
        tq += __shfl_xor(tq, m, 64);
    }
    if (lane == 0) {
        S[node] = make_float2(ap, aq);
        T[node] = make_float2(tp, tq);
    }
}

// layer-2: p[n] = mean_nbrs(S.x) + T.x + c.x ; q likewise. 8B gather per edge.
// 4 lanes per node, 16 nodes per wave.
__global__ void agg2_k(const int* __restrict__ rowptr, const int* __restrict__ adj,
                       const float2* __restrict__ S, const float2* __restrict__ T,
                       const float2* __restrict__ cpq,
                       float* __restrict__ p, float* __restrict__ q) {
    int lane = threadIdx.x & 63;
    int wavei = blockIdx.x * 4 + (threadIdx.x >> 6);
    int slot = lane & 3;
    int node = wavei * 16 + (lane >> 2);
    if (node >= N_NODES) return;
    int beg = rowptr[node], end = rowptr[node + 1];
    float sp = 0.f, sq = 0.f;
    for (int e = beg + slot; e < end; e += 4) {
        float2 v = S[adj[e]];
        sp += v.x; sq += v.y;
    }
    sp += __shfl_xor(sp, 1, 64); sp += __shfl_xor(sp, 2, 64);
    sq += __shfl_xor(sq, 1, 64); sq += __shfl_xor(sq, 2, 64);
    if (slot == 0) {
        int deg = end - beg;
        float inv = deg > 0 ? 1.f / (float)deg : 0.f;
        float2 t = T[node];
        float2 c = *cpq;
        p[node] = sp * inv + t.x + c.x;
        q[node] = sq * inv + t.y + c.y;
    }
}

__global__ void out_k(const int* __restrict__ eli, const float* __restrict__ p,
                      const float* __restrict__ q, const float* __restrict__ blin,
                      float* __restrict__ out) {
    int i = blockIdx.x * blockDim.x + threadIdx.x;
    if (i < N_LABELS) out[i] = p[eli[i]] + q[eli[N_LABELS + i]] + blin[0];
}

// ---------------- launch ----------------

extern "C" void kernel_launch(void* const* d_in, const int* in_sizes, int n_in,
                              void* d_out, int out_size, void* d_ws, size_t ws_size,
                              hipStream_t stream) {
    const int*   edge_index = (const int*)d_in[0];
    const int*   eli        = (const int*)d_in[1];
    const float* emb        = (const float*)d_in[2];
    const float* W1l        = (const float*)d_in[3];
    const float* b1         = (const float*)d_in[4];
    const float* W1r        = (const float*)d_in[5];
    const float* W2l        = (const float*)d_in[6];
    const float* b2         = (const float*)d_in[7];
    const float* W2r        = (const float*)d_in[8];
    const float* Wlin       = (const float*)d_in[9];
    const float* blin       = (const float*)d_in[10];
    float* out = (float*)d_out;

    char* ws = (char*)d_ws;
    size_t off = 0;
    auto alloc = [&](size_t bytes) -> void* {
        off = (off + 255) & ~(size_t)255;
        void* ptr = ws + off;
        off += bytes;
        return ptr;
    };

    short* Hl  = (short*)alloc((size_t)N_NODES * DIM * 2);
    short* Hr  = (short*)alloc((size_t)N_NODES * DIM * 2);
    short* BT1 = (short*)alloc(256 * 128 * 2);
    float* up = (float*)alloc(128 * 4);
    float* uq = (float*)alloc(128 * 4);
    float* vp = (float*)alloc(128 * 4);
    float* vq = (float*)alloc(128 * 4);
    float2* cpq = (float2*)alloc(8);
    int* cnt      = (int*)alloc((size_t)N_NODES * 4);
    int* rowptr   = (int*)alloc((size_t)(N_NODES + 1) * 4);
    int* widx     = (int*)alloc((size_t)N_NODES * 4);
    int* adj      = (int*)alloc((size_t)N_EDGES * 4);
    int* partials = (int*)alloc(NPARTS * 4);
    int* pscan    = (int*)alloc(NPARTS * 4);
    float2* S     = (float2*)alloc((size_t)N_NODES * 8);
    float2* T     = (float2*)alloc((size_t)N_NODES * 8);
    float* p      = (float*)alloc((size_t)N_NODES * 4);
    float* q      = (float*)alloc((size_t)N_NODES * 4);

    hipMemsetAsync(cnt, 0, (size_t)N_NODES * 4, stream);

    prep_k<<<130, 256, 0, stream>>>(W1l, W1r, BT1, W2l, W2r, Wlin, b2, up, uq, vp, vq, cpq);

    // CSR build
    count_k<<<(N_EDGES + 255) / 256, 256, 0, stream>>>(edge_index, cnt);
    scan1_k<<<NPARTS, 256, 0, stream>>>(cnt, rowptr, partials);
    scan2_k<<<1, 512, 0, stream>>>(partials, pscan, rowptr);
    scan3_k<<<NPARTS, 256, 0, stream>>>(rowptr, pscan, widx);
    fill_k<<<(N_EDGES + 255) / 256, 256, 0, stream>>>(edge_index, widx, adj);

    // layer 1 GEMM (emb f32 read + bf16 convert fused)
    gemm_k<<<GEMM_GRID, 256, 0, stream>>>(emb, BT1, Hl, Hr);

    // layer-1 aggregation fused with layer-2 projections
    agg1_k<<<N_NODES / 4, 256, 0, stream>>>(Hl, Hr, rowptr, adj, b1, up, uq, vp, vq, S, T);

    // layer-2 (scalar gather) + predictor
    agg2_k<<<(N_NODES + 63) / 64, 256, 0, stream>>>(rowptr, adj, S, T, cpq, p, q);
    out_k<<<(N_LABELS + 255) / 256, 256, 0, stream>>>(eli, p, q, blin, out);
}